// Round 13
// baseline (132.550 us; speedup 1.0000x reference)
//
#include <hip/hip_runtime.h>
#include <math.h>

#define B_ 2
#define N_ 400
#define F_ 246
#define C_ 32
#define LBL_ 1440
#define NODE_IN_ 310  // F + 2C

#define KX_ 320   // Abuf row: 246 x | 32 aggi | 32 aggj | 10 pad (pad holds
                  // poison; consumers' weights there are 0.0 -> harmless)
#define KN_ 256   // node output cols padded 246 -> 256

#define T_ABUF (800 * KX_)
#define T_WNT  (256 * KX_)
#define T_WOT  (LBL_ * KN_)

typedef __attribute__((ext_vector_type(8))) short bf16x8;  // 8 bf16, 4 VGPRs
typedef __attribute__((ext_vector_type(4))) float f32x4;

__device__ __forceinline__ short f2bf(float f) {           // RNE fp32->bf16
    unsigned u = __float_as_uint(f);
    return (short)((u + 0x7FFF + ((u >> 16) & 1)) >> 16);
}

// MFMA layouts (HW-verified m89/m120): A[m=lane&15][k=quad*8+j];
// BT row-major [n][k] (8 consecutive k per lane); C/D col=lane&15, row=quad*4+reg.
template <int K>
__device__ __forceinline__ f32x4 mfma_tile(const short* __restrict__ A,
                                           const short* __restrict__ BT,
                                           int m0, int n0, int lane) {
    int r = lane & 15, quad = lane >> 4;
    const short* ap = A + (size_t)(m0 + r) * K + quad * 8;
    const short* bp = BT + (size_t)(n0 + r) * K + quad * 8;
    f32x4 acc = {0.f, 0.f, 0.f, 0.f};
    #pragma unroll
    for (int kk = 0; kk < K; kk += 32) {
        bf16x8 av = *(const bf16x8*)(ap + kk);
        bf16x8 bv = *(const bf16x8*)(bp + kk);
        acc = __builtin_amdgcn_mfma_f32_16x16x32_bf16(av, bv, acc, 0, 0, 0);
    }
    return acc;
}

// ---------------------------------------------------------------------------
// K1 k_pre (one dispatch, block ranges):
//  [0,50):    PQ[800][64] MFMA, frags built inline from fp32 x / Ws (L2-hot,
//             bit-identical to staged path). Block = 4 waves = 4 n-tiles.
//  [50,150):  Abuf[row][0:246] = bf16(x), 8 rows/block (agg cols by k_agg)
//  [150,510): WoT[1440][256] = bf16(Wo^T), LDS 32x32 tiles (coalesced R+W)
//  [510,590): WnT[256][320]  = bf16(Wn^T) zero-padded, LDS tiles
// ---------------------------------------------------------------------------
__global__ void k_pre(const float* __restrict__ x, const float* __restrict__ Ws,
                      const float* __restrict__ Wn, const float* __restrict__ Wo,
                      float* __restrict__ PQ, short* __restrict__ Abuf,
                      short* __restrict__ WnT, short* __restrict__ WoT) {
    __shared__ short tile[32][33];
    int bx = blockIdx.x, tid = threadIdx.x;
    if (bx < 50) {                       // ---- PQ MFMA, no staging dependency
        int w = tid >> 6, lane = tid & 63;
        int m0 = bx * 16, n = w * 16 + (lane & 15);   // n in [0,64)
        int r = lane & 15, quad = lane >> 4;
        const float* xrow = x + (size_t)(m0 + r) * F_;
        f32x4 acc = {0.f, 0.f, 0.f, 0.f};
        #pragma unroll
        for (int kk = 0; kk < 256; kk += 32) {
            int kb = kk + quad * 8;
            bf16x8 av, bv;
            #pragma unroll
            for (int j = 0; j < 8; ++j) {
                int k = kb + j;
                av[j] = (k < F_) ? f2bf(xrow[k]) : (short)0;
                float f = 0.f;
                if (k < F_) f = (n < C_) ? Ws[k * C_ + n]
                                         : Ws[(F_ + k) * C_ + (n - C_)];
                bv[j] = f2bf(f);
            }
            acc = __builtin_amdgcn_mfma_f32_16x16x32_bf16(av, bv, acc, 0, 0, 0);
        }
        int mb = m0 + quad * 4;
        #pragma unroll
        for (int rr = 0; rr < 4; ++rr)
            PQ[(size_t)(mb + rr) * 64 + n] = acc[rr];
        return;
    }
    bx -= 50;
    if (bx < 100) {                      // ---- Abuf x staging, 8 rows/block
        int r0 = bx * 8;
        for (int idx = tid; idx < 8 * F_; idx += 256) {
            int lr = idx / F_, k = idx - lr * F_;
            Abuf[(size_t)(r0 + lr) * KX_ + k] = f2bf(x[(size_t)(r0 + lr) * F_ + k]);
        }
        return;
    }
    bx -= 100;
    int tx = tid & 31, ty = tid >> 5;    // 32 x 8
    if (bx < 360) {                      // ---- WoT[n][k] = Wo[k][n]
        int n0 = (bx % 45) * 32, k0 = (bx / 45) * 32;
        #pragma unroll
        for (int r = 0; r < 4; ++r) {
            int k = k0 + ty + r * 8;
            tile[ty + r * 8][tx] = (k < F_) ? f2bf(Wo[k * LBL_ + n0 + tx]) : (short)0;
        }
        __syncthreads();
        #pragma unroll
        for (int r = 0; r < 4; ++r)
            WoT[(size_t)(n0 + ty + r * 8) * KN_ + k0 + tx] = tile[tx][ty + r * 8];
        return;
    }
    bx -= 360;
    {                                    // ---- WnT[n][k] = Wn[k][n] (padded)
        int n0 = (bx % 8) * 32, k0 = (bx / 8) * 32;
        #pragma unroll
        for (int r = 0; r < 4; ++r) {
            int k = k0 + ty + r * 8, n = n0 + tx;
            tile[ty + r * 8][tx] =
                (n < F_ && k < NODE_IN_) ? f2bf(Wn[k * F_ + n]) : (short)0;
        }
        __syncthreads();
        #pragma unroll
        for (int r = 0; r < 4; ++r)
            WnT[(size_t)(n0 + ty + r * 8) * KX_ + k0 + tx] = tile[tx][ty + r * 8];
    }
}

// ---------------------------------------------------------------------------
// K2 k_agg: sparse aggregation (fp32 VALU) -> bf16 agg cols of Abuf.
// grid = 1600 blocks x 256 thr (8 groups x 32 lanes, lane = channel).
// ---------------------------------------------------------------------------
__global__ void k_agg(const float* __restrict__ a, const float* __restrict__ e,
                      const float* __restrict__ Ws, const float* __restrict__ bs,
                      const float* __restrict__ alpha,
                      const float* __restrict__ Wai, const float* __restrict__ bai,
                      const float* __restrict__ Waj, const float* __restrict__ baj,
                      const float* __restrict__ PQ, short* __restrict__ Abuf) {
    int blk  = blockIdx.x;
    int mode = (blk >= B_ * N_) ? 1 : 0;
    int row  = mode ? blk - B_ * N_ : blk;   // b*N + n
    int b = row / N_, n = row % N_;
    int tid = threadIdx.x;
    int c = tid & 31, g = tid >> 5;

    float w3  = Ws[(2 * F_) * C_ + c];
    float w4  = Ws[(2 * F_ + 1) * C_ + c];
    float bsc = bs[c];
    float alc = alpha[c];
    float wat = mode ? Waj[c] : Wai[c];
    float bat = mode ? baj[0] : bai[0];

    float ownc = PQ[(size_t)row * 64 + (mode ? 32 : 0) + c];
    const float* oth = PQ + (size_t)b * N_ * 64 + (mode ? 0 : 32) + c;
    const float* abase = a + (size_t)b * N_ * N_;
    const float* ebase = e + (size_t)b * N_ * N_;

    float acc = 0.f;
    #pragma unroll 4
    for (int m = g; m < N_; m += 8) {
        float aij  = mode ? abase[m * N_ + n] : abase[n * N_ + m];
        float er   = ebase[n * N_ + m];
        float ec   = ebase[m * N_ + n];
        float othv = oth[(size_t)m * 64];
        if (aij != 0.f) {                    // uniform per 32-lane group
            float eij = mode ? ec : er;
            float eji = mode ? er : ec;
            float raw = ownc + othv + eij * w3 + eji * w4 + bsc;
            float s = (raw >= 0.f ? raw : alc * raw) * aij;
            float t2 = s * wat;              // 32-ch butterfly dot
            t2 += __shfl_xor(t2, 1, 32);
            t2 += __shfl_xor(t2, 2, 32);
            t2 += __shfl_xor(t2, 4, 32);
            t2 += __shfl_xor(t2, 8, 32);
            t2 += __shfl_xor(t2, 16, 32);
            float att = 1.f / (1.f + __expf(-(t2 + bat)));
            acc += s * att;
        }
    }
    __shared__ float part[8][C_ + 1];
    part[g][c] = acc;
    __syncthreads();
    if (tid < C_) {
        float tot = 0.f;
        #pragma unroll
        for (int gg = 0; gg < 8; ++gg) tot += part[gg][tid];
        // Abuf agg cols: mode 0 -> 246..277 (agg_i), mode 1 -> 278..309
        Abuf[(size_t)row * KX_ + F_ + mode * C_ + tid] = f2bf(tot);
    }
}

// ---------------------------------------------------------------------------
// K3 k_nodeout: node + out fused at m-tile granularity (block-local sync).
// grid = (50, 5), 1024 thr = 16 waves. Block (bx, ns): rows m0=bx*16.
//  phase A: 16 waves compute the 16x256 node tile -> LDS (bf16, +bias, pad 0)
//  phase B: out n-tiles ns*18..ns*18+17 (A-frags from LDS, B from WoT).
// Node recomputed 5x (cheap MFMA) to keep 250 blocks of parallelism.
// LDS row stride 264 (528B, 16B-aligned, !=0 mod 32 banks) -> no 16-way
// conflict on ds_read_b128.
// ---------------------------------------------------------------------------
__global__ __launch_bounds__(1024, 1)
void k_nodeout(const short* __restrict__ Abuf, const short* __restrict__ WnT,
               const float* __restrict__ bn, const short* __restrict__ WoT,
               const float* __restrict__ bo, float* __restrict__ out) {
    __shared__ short Xs[16][264];
    int tid = threadIdx.x;
    int w = tid >> 6, lane = tid & 63;
    int m0 = blockIdx.x * 16;
    int col = lane & 15, quad = lane >> 4;

    // phase A: node tile n0 = w*16
    {
        int n0 = w * 16;
        f32x4 acc = mfma_tile<KX_>(Abuf, WnT, m0, n0, lane);
        int nn = n0 + col;
        float bv = (nn < F_) ? bn[nn] : 0.f;
        #pragma unroll
        for (int r = 0; r < 4; ++r)
            Xs[quad * 4 + r][nn] = (nn < F_) ? f2bf(acc[r] + bv) : (short)0;
    }
    __syncthreads();

    // phase B: out tiles
    const short* xbase = &Xs[0][0];
    for (int tt = w; tt < 18; tt += 16) {
        int n0 = (blockIdx.y * 18 + tt) * 16;
        int r = lane & 15;
        const short* ap = xbase + r * 264 + quad * 8;
        const short* bp = WoT + (size_t)(n0 + r) * KN_ + quad * 8;
        f32x4 acc = {0.f, 0.f, 0.f, 0.f};
        #pragma unroll
        for (int kk = 0; kk < KN_; kk += 32) {
            bf16x8 av = *(const bf16x8*)(ap + kk);
            bf16x8 bv = *(const bf16x8*)(bp + kk);
            acc = __builtin_amdgcn_mfma_f32_16x16x32_bf16(av, bv, acc, 0, 0, 0);
        }
        int nn = n0 + col;
        float bv = bo[nn];
        #pragma unroll
        for (int rr = 0; rr < 4; ++rr)
            out[(size_t)(m0 + quad * 4 + rr) * LBL_ + nn] = acc[rr] + bv;
    }
}

// ---------------------------------------------------------------------------
extern "C" void kernel_launch(void* const* d_in, const int* in_sizes, int n_in,
                              void* d_out, int out_size, void* d_ws, size_t ws_size,
                              hipStream_t stream) {
    const float* x   = (const float*)d_in[0];
    const float* a   = (const float*)d_in[1];
    const float* e   = (const float*)d_in[2];
    const float* Ws  = (const float*)d_in[3];
    const float* bs  = (const float*)d_in[4];
    const float* al  = (const float*)d_in[5];
    const float* Wai = (const float*)d_in[6];
    const float* bai = (const float*)d_in[7];
    const float* Waj = (const float*)d_in[8];
    const float* baj = (const float*)d_in[9];
    const float* Wn  = (const float*)d_in[10];
    const float* bn  = (const float*)d_in[11];
    const float* Wo  = (const float*)d_in[12];
    const float* bo  = (const float*)d_in[13];

    float* PQ   = (float*)d_ws;                   // 800*64 f32
    short* Abuf = (short*)(PQ + 800 * 64);        // 800*320 bf16 (16B-aligned)
    short* WnT  = Abuf + T_ABUF;                  // 256*320
    short* WoT  = WnT + T_WNT;                    // 1440*256

    k_pre<<<590, 256, 0, stream>>>(x, Ws, Wn, Wo, PQ, Abuf, WnT, WoT);
    k_agg<<<2 * B_ * N_, 256, 0, stream>>>(a, e, Ws, bs, al, Wai, bai, Waj, baj,
                                           PQ, Abuf);
    k_nodeout<<<dim3(50, 5), 1024, 0, stream>>>(Abuf, WnT, bn, WoT, bo,
                                                (float*)d_out);
}